// Round 2
// baseline (682.335 us; speedup 1.0000x reference)
//
#include <hip/hip_runtime.h>
#include <hip/hip_bf16.h>

#define U_NUM 100000
#define I_NUM 50000
#define N_NUM 150000
#define E_NUM 1200000
#define D 64
#define F_IT 384
#define CAP 48
#define EPSV 1e-8f

// ---------------- bucket build ----------------
__global__ void k_zero(int* p, int n) {
    int i = blockIdx.x * 256 + threadIdx.x;
    if (i < n) p[i] = 0;
}

__global__ void k_fill(const int* __restrict__ row, const int* __restrict__ col,
                       const float* __restrict__ val,
                       int* __restrict__ cnt, int2* __restrict__ bkt) {
    int e = blockIdx.x * 256 + threadIdx.x;
    if (e >= E_NUM) return;
    int r = row[e];
    int pos = atomicAdd(&cnt[r], 1);
    if (pos < CAP) {
        bkt[r * CAP + pos] = make_int2(col[e], __float_as_int(val[e]));
    }
}

// ---------------- ego: users ----------------
__global__ void k_user(const float* __restrict__ ufea, const float* __restrict__ gu,
                       float* __restrict__ ego, float* __restrict__ acc) {
    int i = blockIdx.x * 256 + threadIdx.x;   // exact U*D grid
    int d = i & 63;
    float g = gu[d] + gu[64 + d] + gu[128 + d];
    float v = ufea[i] + g;
    ego[i] = v;
    acc[i] = v;
}

// ---------------- ego: items (MLP + tanh) ----------------
// block: 256 threads = 8 items x 32 dims; grid (I/8, 2 dim-halves)
__global__ __launch_bounds__(256) void k_item(const float* __restrict__ ifea,
                                              const float* __restrict__ w,
                                              const float* __restrict__ b,
                                              const float* __restrict__ gi,
                                              float* __restrict__ ego, float* __restrict__ acc) {
    __shared__ float wf[32][F_IT + 1];   // +1 pad -> bank-conflict free
    __shared__ float fs[8][F_IT];
    int t = threadIdx.x;
    int dbase = blockIdx.y * 32;
    int ibase = blockIdx.x * 8;

    // stage 32 weight rows (fp32, coalesced float4)
    for (int idx = t; idx < 32 * F_IT / 4; idx += 256) {
        int dd = idx / (F_IT / 4), kk = idx - dd * (F_IT / 4);
        float4 v = ((const float4*)w)[(size_t)(dbase + dd) * (F_IT / 4) + kk];
        wf[dd][kk * 4 + 0] = v.x; wf[dd][kk * 4 + 1] = v.y;
        wf[dd][kk * 4 + 2] = v.z; wf[dd][kk * 4 + 3] = v.w;
    }
    // stage 8 item feature rows
    for (int idx = t; idx < 8 * F_IT / 4; idx += 256) {
        int ii = idx / (F_IT / 4), kk = idx - ii * (F_IT / 4);
        float4 v = ((const float4*)ifea)[(size_t)(ibase + ii) * (F_IT / 4) + kk];
        fs[ii][kk * 4 + 0] = v.x; fs[ii][kk * 4 + 1] = v.y;
        fs[ii][kk * 4 + 2] = v.z; fs[ii][kk * 4 + 3] = v.w;
    }
    __syncthreads();

    int il = t >> 5, d = t & 31;
    float s = 0.f;
#pragma unroll 8
    for (int k = 0; k < F_IT; k++) s += fs[il][k] * wf[d][k];

    int dg = dbase + d;
    float g = gi[dg] + gi[64 + dg] + gi[128 + dg];
    float v = tanhf(s + b[dg]) + g;
    size_t o = (size_t)(U_NUM + ibase + il) * D + dg;
    ego[o] = v;
    acc[o] = v;
}

// ---------------- ego norms ----------------
__global__ void k_norm(const float* __restrict__ ego, float* __restrict__ nrm) {
    int t = blockIdx.x * 256 + threadIdx.x;   // exact N*16 grid
    int r = t >> 4, l = t & 15;
    float4 e = ((const float4*)ego)[r * 16 + l];
    float s = e.x * e.x + e.y * e.y + e.z * e.z + e.w * e.w;
    s += __shfl_xor(s, 1);
    s += __shfl_xor(s, 2);
    s += __shfl_xor(s, 4);
    s += __shfl_xor(s, 8);
    if (l == 0) nrm[r] = fmaxf(sqrtf(s), EPSV);
}

// ---------------- one GCN layer: SpMM + cosine rescale + acc, fused ----------------
// quarter-wave (16 lanes, float4) per row; block = 16 rows
__global__ __launch_bounds__(256) void k_spmm(const float* __restrict__ x,
                                              const float* __restrict__ ego,
                                              const float* __restrict__ nrm,
                                              const int* __restrict__ cnt,
                                              const int2* __restrict__ bkt,
                                              float* __restrict__ xo, float* __restrict__ acc) {
    int t = blockIdx.x * 256 + threadIdx.x;   // exact N*16 grid
    int r = t >> 4, l = t & 15;
    int deg = min(cnt[r], CAP);
    int base = r * CAP;
    float4 a = make_float4(0.f, 0.f, 0.f, 0.f);
    for (int j = 0; j < deg; j++) {
        int2 cv = bkt[base + j];
        float v = __int_as_float(cv.y);
        float4 xv = ((const float4*)x)[(size_t)cv.x * 16 + l];
        a.x += v * xv.x; a.y += v * xv.y; a.z += v * xv.z; a.w += v * xv.w;
    }
    float4 e = ((const float4*)ego)[(size_t)r * 16 + l];
    float dot = a.x * e.x + a.y * e.y + a.z * e.z + a.w * e.w;
    float nx  = a.x * a.x + a.y * a.y + a.z * a.z + a.w * a.w;
#pragma unroll
    for (int m = 1; m < 16; m <<= 1) {
        dot += __shfl_xor(dot, m);
        nx  += __shfl_xor(nx, m);
    }
    float wgt = dot / (fmaxf(sqrtf(nx), EPSV) * nrm[r]);
    float4 o = make_float4(wgt * a.x, wgt * a.y, wgt * a.z, wgt * a.w);
    size_t oi = (size_t)r * 16 + l;
    ((float4*)xo)[oi] = o;
    float4 av = ((const float4*)acc)[oi];
    av.x += o.x; av.y += o.y; av.z += o.z; av.w += o.w;
    ((float4*)acc)[oi] = av;
}

extern "C" void kernel_launch(void* const* d_in, const int* in_sizes, int n_in,
                              void* d_out, int out_size, void* d_ws, size_t ws_size,
                              hipStream_t stream) {
    const int*   adj_row  = (const int*)d_in[0];
    const int*   adj_col  = (const int*)d_in[1];
    const float* adj_val  = (const float*)d_in[2];
    const float* user_fea = (const float*)d_in[3];
    const float* item_fea = (const float*)d_in[4];
    const float* gu       = (const float*)d_in[5];
    const float* gi       = (const float*)d_in[6];
    const float* mlp_w    = (const float*)d_in[7];
    const float* mlp_b    = (const float*)d_in[8];

    // acc lives directly in d_out: output = concat(acc_user, acc_item) = acc
    float* acc = (float*)d_out;

    char* ws = (char*)d_ws;
    size_t off = 0;
    float* ego = (float*)(ws + off); off += (size_t)N_NUM * D * 4;
    float* xA  = (float*)(ws + off); off += (size_t)N_NUM * D * 4;
    float* xB  = (float*)(ws + off); off += (size_t)N_NUM * D * 4;
    float* nrm = (float*)(ws + off); off += (size_t)N_NUM * 4;
    int*   cnt = (int*)(ws + off);   off += (size_t)N_NUM * 4;
    int2*  bkt = (int2*)(ws + off);  off += (size_t)N_NUM * CAP * 8;

    k_zero<<<(N_NUM + 255) / 256, 256, 0, stream>>>(cnt, N_NUM);
    k_fill<<<(E_NUM + 255) / 256, 256, 0, stream>>>(adj_row, adj_col, adj_val, cnt, bkt);
    k_user<<<U_NUM * D / 256, 256, 0, stream>>>(user_fea, gu, ego, acc);
    k_item<<<dim3(I_NUM / 8, 2), 256, 0, stream>>>(item_fea, mlp_w, mlp_b, gi, ego, acc);
    k_norm<<<N_NUM * 16 / 256, 256, 0, stream>>>(ego, nrm);

    // 4 GCN layers, ping-pong x buffers (layer-1 input is ego itself)
    k_spmm<<<N_NUM * 16 / 256, 256, 0, stream>>>(ego, ego, nrm, cnt, bkt, xA, acc);
    k_spmm<<<N_NUM * 16 / 256, 256, 0, stream>>>(xA,  ego, nrm, cnt, bkt, xB, acc);
    k_spmm<<<N_NUM * 16 / 256, 256, 0, stream>>>(xB,  ego, nrm, cnt, bkt, xA, acc);
    k_spmm<<<N_NUM * 16 / 256, 256, 0, stream>>>(xA,  ego, nrm, cnt, bkt, xB, acc);
}

// Round 3
// 470.210 us; speedup vs baseline: 1.4511x; 1.4511x over previous
//
#include <hip/hip_runtime.h>
#include <hip/hip_bf16.h>

#define U_NUM 100000
#define I_NUM 50000
#define N_NUM 150000
#define E_NUM 1200000
#define D 64
#define F_IT 384
#define CAP 48
#define EPSV 1e-8f

typedef unsigned short ushort_t;
typedef unsigned int uint_t;
typedef short bf16x8 __attribute__((ext_vector_type(8)));
typedef float f32x4 __attribute__((ext_vector_type(4)));

__device__ __forceinline__ ushort_t f2bf(float f) {
    uint_t x = __float_as_uint(f);
    uint_t r = x + 0x7fffu + ((x >> 16) & 1u);   // round-to-nearest-even
    return (ushort_t)(r >> 16);
}
__device__ __forceinline__ float bfu2f(uint_t u_lo16) {
    return __uint_as_float(u_lo16 << 16);
}

// ---------------- bucket build ----------------
__global__ void k_zero(int* p, int n) {
    int i = blockIdx.x * 256 + threadIdx.x;
    if (i < n) p[i] = 0;
}

__global__ void k_fill(const int* __restrict__ row, const int* __restrict__ col,
                       const float* __restrict__ val,
                       int* __restrict__ cnt, int2* __restrict__ bkt) {
    int e = blockIdx.x * 256 + threadIdx.x;
    if (e >= E_NUM) return;
    int r = row[e];
    int pos = atomicAdd(&cnt[r], 1);
    if (pos < CAP) {
        bkt[r * CAP + pos] = make_int2(col[e], __float_as_int(val[e]));
    }
}

// ---------------- weights fp32 -> bf16 (L2-resident operand for MFMA) ----------------
__global__ void k_wcast(const float* __restrict__ w, short* __restrict__ wbf) {
    int i = blockIdx.x * 256 + threadIdx.x;   // exact 64*384/256 grid
    wbf[i] = (short)f2bf(w[i]);
}

// ---------------- ego: users ----------------
__global__ void k_user(const float* __restrict__ ufea, const float* __restrict__ gu,
                       float* __restrict__ ego, float* __restrict__ acc,
                       ushort_t* __restrict__ egob) {
    int i = blockIdx.x * 256 + threadIdx.x;   // exact U*D grid
    int d = i & 63;
    float g = gu[d] + gu[64 + d] + gu[128 + d];
    float v = ufea[i] + g;
    ego[i] = v;
    acc[i] = v;
    egob[i] = f2bf(v);
}

// ---------------- ego: items (MLP via MFMA, no LDS) ----------------
// block = 4 waves; each wave: 16 items x 64 dims, K=384 in 12 chunks of 32.
// A-frag: 8 contiguous fp32 of fea row (streamed, cast to bf16 in regs).
// B-frag: 8 contiguous bf16 of wbf row (48KB total, L2-resident).
__global__ __launch_bounds__(256) void k_item(const float* __restrict__ ifea,
                                              const short* __restrict__ wbf,
                                              const float* __restrict__ b,
                                              const float* __restrict__ gi,
                                              float* __restrict__ ego, float* __restrict__ acc,
                                              ushort_t* __restrict__ egob) {
    int wave = threadIdx.x >> 6;
    int lane = threadIdx.x & 63;
    int q = lane >> 4, m = lane & 15;
    int ibase = blockIdx.x * 64 + wave * 16;

    int irow = min(ibase + m, I_NUM - 1);
    const float* arow = ifea + (size_t)irow * F_IT + q * 8;

    f32x4 av[4];
#pragma unroll
    for (int n = 0; n < 4; n++) av[n] = (f32x4){0.f, 0.f, 0.f, 0.f};

#pragma unroll
    for (int c = 0; c < 12; c++) {
        float4 fa0 = ((const float4*)(arow + c * 32))[0];
        float4 fa1 = ((const float4*)(arow + c * 32))[1];
        bf16x8 af;
        af[0] = (short)f2bf(fa0.x); af[1] = (short)f2bf(fa0.y);
        af[2] = (short)f2bf(fa0.z); af[3] = (short)f2bf(fa0.w);
        af[4] = (short)f2bf(fa1.x); af[5] = (short)f2bf(fa1.y);
        af[6] = (short)f2bf(fa1.z); af[7] = (short)f2bf(fa1.w);
#pragma unroll
        for (int n = 0; n < 4; n++) {
            bf16x8 bf = *(const bf16x8*)(wbf + (size_t)(n * 16 + m) * F_IT + c * 32 + q * 8);
            av[n] = __builtin_amdgcn_mfma_f32_16x16x32_bf16(af, bf, av[n], 0, 0, 0);
        }
    }

    // C/D layout: col = lane&15 (= dim within 16), row = (lane>>4)*4 + reg (= item)
#pragma unroll
    for (int n = 0; n < 4; n++) {
        int dim = n * 16 + m;
        float bb = b[dim];
        float gg = gi[dim] + gi[64 + dim] + gi[128 + dim];
#pragma unroll
        for (int r = 0; r < 4; r++) {
            int item = ibase + q * 4 + r;
            if (item < I_NUM) {
                float v = tanhf(av[n][r] + bb) + gg;
                size_t o = (size_t)(U_NUM + item) * D + dim;
                ego[o] = v;
                acc[o] = v;
                egob[o] = f2bf(v);
            }
        }
    }
}

// ---------------- ego norms ----------------
__global__ void k_norm(const float* __restrict__ ego, float* __restrict__ nrm) {
    int t = blockIdx.x * 256 + threadIdx.x;   // exact N*16 grid
    int r = t >> 4, l = t & 15;
    float4 e = ((const float4*)ego)[r * 16 + l];
    float s = e.x * e.x + e.y * e.y + e.z * e.z + e.w * e.w;
    s += __shfl_xor(s, 1);
    s += __shfl_xor(s, 2);
    s += __shfl_xor(s, 4);
    s += __shfl_xor(s, 8);
    if (l == 0) nrm[r] = fmaxf(sqrtf(s), EPSV);
}

// ---------------- one GCN layer: bf16-gather SpMM + cosine rescale + acc ----------------
// 8 lanes per row, each lane: 8 dims. Gather = 1 dwordx4 (8 bf16) per edge per lane.
__global__ __launch_bounds__(256) void k_spmm(const ushort_t* __restrict__ xb,
                                              const float* __restrict__ ego,
                                              const float* __restrict__ nrm,
                                              const int* __restrict__ cnt,
                                              const int2* __restrict__ bkt,
                                              ushort_t* __restrict__ xob,
                                              float* __restrict__ acc) {
    int t = blockIdx.x * 256 + threadIdx.x;
    int r = t >> 3, l = t & 7;
    if (r >= N_NUM) return;
    int deg = min(cnt[r], CAP);
    int base = r * CAP;

    float a[8];
#pragma unroll
    for (int j = 0; j < 8; j++) a[j] = 0.f;

    for (int j = 0; j < deg; j++) {
        int2 cv = bkt[base + j];
        float v = __int_as_float(cv.y);
        uint4 xv = ((const uint4*)xb)[(size_t)cv.x * 8 + l];
        a[0] += v * bfu2f(xv.x & 0xffffu); a[1] += v * bfu2f(xv.x >> 16);
        a[2] += v * bfu2f(xv.y & 0xffffu); a[3] += v * bfu2f(xv.y >> 16);
        a[4] += v * bfu2f(xv.z & 0xffffu); a[5] += v * bfu2f(xv.z >> 16);
        a[6] += v * bfu2f(xv.w & 0xffffu); a[7] += v * bfu2f(xv.w >> 16);
    }

    const float4* ep = (const float4*)(ego + (size_t)r * D + l * 8);
    float4 e0 = ep[0], e1 = ep[1];
    float dot = a[0] * e0.x + a[1] * e0.y + a[2] * e0.z + a[3] * e0.w
              + a[4] * e1.x + a[5] * e1.y + a[6] * e1.z + a[7] * e1.w;
    float nx = a[0] * a[0] + a[1] * a[1] + a[2] * a[2] + a[3] * a[3]
             + a[4] * a[4] + a[5] * a[5] + a[6] * a[6] + a[7] * a[7];
    dot += __shfl_xor(dot, 1); nx += __shfl_xor(nx, 1);
    dot += __shfl_xor(dot, 2); nx += __shfl_xor(nx, 2);
    dot += __shfl_xor(dot, 4); nx += __shfl_xor(nx, 4);
    float wgt = dot / (fmaxf(sqrtf(nx), EPSV) * nrm[r]);

    float o[8];
#pragma unroll
    for (int j = 0; j < 8; j++) o[j] = wgt * a[j];

    uint4 ov;
    ov.x = (uint_t)f2bf(o[0]) | ((uint_t)f2bf(o[1]) << 16);
    ov.y = (uint_t)f2bf(o[2]) | ((uint_t)f2bf(o[3]) << 16);
    ov.z = (uint_t)f2bf(o[4]) | ((uint_t)f2bf(o[5]) << 16);
    ov.w = (uint_t)f2bf(o[6]) | ((uint_t)f2bf(o[7]) << 16);
    ((uint4*)xob)[(size_t)r * 8 + l] = ov;

    float4* ap = (float4*)(acc + (size_t)r * D + l * 8);
    float4 a0 = ap[0], a1 = ap[1];
    a0.x += o[0]; a0.y += o[1]; a0.z += o[2]; a0.w += o[3];
    a1.x += o[4]; a1.y += o[5]; a1.z += o[6]; a1.w += o[7];
    ap[0] = a0; ap[1] = a1;
}

extern "C" void kernel_launch(void* const* d_in, const int* in_sizes, int n_in,
                              void* d_out, int out_size, void* d_ws, size_t ws_size,
                              hipStream_t stream) {
    const int*   adj_row  = (const int*)d_in[0];
    const int*   adj_col  = (const int*)d_in[1];
    const float* adj_val  = (const float*)d_in[2];
    const float* user_fea = (const float*)d_in[3];
    const float* item_fea = (const float*)d_in[4];
    const float* gu       = (const float*)d_in[5];
    const float* gi       = (const float*)d_in[6];
    const float* mlp_w    = (const float*)d_in[7];
    const float* mlp_b    = (const float*)d_in[8];

    float* acc = (float*)d_out;   // output = concat(acc_user, acc_item)

    char* ws = (char*)d_ws;
    size_t off = 0;
    float*    ego  = (float*)(ws + off);    off += (size_t)N_NUM * D * 4;
    ushort_t* egob = (ushort_t*)(ws + off); off += (size_t)N_NUM * D * 2;
    ushort_t* xA   = (ushort_t*)(ws + off); off += (size_t)N_NUM * D * 2;
    ushort_t* xB   = (ushort_t*)(ws + off); off += (size_t)N_NUM * D * 2;
    float*    nrm  = (float*)(ws + off);    off += (size_t)N_NUM * 4;
    int*      cnt  = (int*)(ws + off);      off += (size_t)N_NUM * 4;
    short*    wbf  = (short*)(ws + off);    off += (size_t)D * F_IT * 2;
    off = (off + 255) & ~(size_t)255;
    int2*     bkt  = (int2*)(ws + off);     off += (size_t)N_NUM * CAP * 8;

    k_zero<<<(N_NUM + 255) / 256, 256, 0, stream>>>(cnt, N_NUM);
    k_fill<<<(E_NUM + 255) / 256, 256, 0, stream>>>(adj_row, adj_col, adj_val, cnt, bkt);
    k_wcast<<<D * F_IT / 256, 256, 0, stream>>>(mlp_w, wbf);
    k_user<<<U_NUM * D / 256, 256, 0, stream>>>(user_fea, gu, ego, acc, egob);
    k_item<<<(I_NUM + 63) / 64, 256, 0, stream>>>(item_fea, wbf, mlp_b, gi, ego, acc, egob);
    k_norm<<<N_NUM * 16 / 256, 256, 0, stream>>>(ego, nrm);

    int g = (N_NUM * 8 + 255) / 256;
    k_spmm<<<g, 256, 0, stream>>>(egob, ego, nrm, cnt, bkt, xA, acc);
    k_spmm<<<g, 256, 0, stream>>>(xA,   ego, nrm, cnt, bkt, xB, acc);
    k_spmm<<<g, 256, 0, stream>>>(xB,   ego, nrm, cnt, bkt, xA, acc);
    k_spmm<<<g, 256, 0, stream>>>(xA,   ego, nrm, cnt, bkt, xB, acc);
}

// Round 4
// 429.587 us; speedup vs baseline: 1.5884x; 1.0946x over previous
//
#include <hip/hip_runtime.h>
#include <hip/hip_bf16.h>

#define U_NUM 100000
#define I_NUM 50000
#define N_NUM 150000
#define E_NUM 1200000
#define D 64
#define F_IT 384
#define CAP 32
#define EPSV 1e-8f

typedef unsigned short ushort_t;
typedef unsigned int uint_t;
typedef short bf16x8 __attribute__((ext_vector_type(8)));
typedef float f32x4 __attribute__((ext_vector_type(4)));

__device__ __forceinline__ ushort_t f2bf(float f) {
    uint_t x = __float_as_uint(f);
    uint_t r = x + 0x7fffu + ((x >> 16) & 1u);   // round-to-nearest-even
    return (ushort_t)(r >> 16);
}
__device__ __forceinline__ float bfu2f(uint_t u_lo16) {
    return __uint_as_float(u_lo16 << 16);
}

// ---------------- bucket build ----------------
__global__ void k_zero(int* p, int n) {
    int i = blockIdx.x * 256 + threadIdx.x;
    if (i < n) p[i] = 0;
}

// 4 edges/thread for memory-level parallelism (atomic+scatter latency-bound)
__global__ void k_fill(const int* __restrict__ row, const int* __restrict__ col,
                       const float* __restrict__ val,
                       int* __restrict__ cnt, int2* __restrict__ bkt) {
    int t = blockIdx.x * 256 + threadIdx.x;
    if (t >= E_NUM / 4) return;
    int r[4], c[4];
    float v[4];
#pragma unroll
    for (int k = 0; k < 4; k++) {
        int e = t + k * (E_NUM / 4);
        r[k] = row[e]; c[k] = col[e]; v[k] = val[e];
    }
    int p[4];
#pragma unroll
    for (int k = 0; k < 4; k++) p[k] = atomicAdd(&cnt[r[k]], 1);
#pragma unroll
    for (int k = 0; k < 4; k++) {
        if (p[k] < CAP) bkt[r[k] * CAP + p[k]] = make_int2(c[k], __float_as_int(v[k]));
    }
}

// ---------------- weights fp32 -> bf16 (L2-resident operand for MFMA) ----------------
__global__ void k_wcast(const float* __restrict__ w, short* __restrict__ wbf) {
    int i = blockIdx.x * 256 + threadIdx.x;   // exact 64*384/256 grid
    wbf[i] = (short)f2bf(w[i]);
}

// ---------------- ego: users ----------------
__global__ void k_user(const float* __restrict__ ufea, const float* __restrict__ gu,
                       float* __restrict__ ego, ushort_t* __restrict__ egob) {
    int i = blockIdx.x * 256 + threadIdx.x;   // exact U*D grid
    int d = i & 63;
    float g = gu[d] + gu[64 + d] + gu[128 + d];
    float v = ufea[i] + g;
    ego[i] = v;
    egob[i] = f2bf(v);
}

// ---------------- ego: items (MLP via MFMA, no LDS) ----------------
__global__ __launch_bounds__(256) void k_item(const float* __restrict__ ifea,
                                              const short* __restrict__ wbf,
                                              const float* __restrict__ b,
                                              const float* __restrict__ gi,
                                              float* __restrict__ ego,
                                              ushort_t* __restrict__ egob) {
    int wave = threadIdx.x >> 6;
    int lane = threadIdx.x & 63;
    int q = lane >> 4, m = lane & 15;
    int ibase = blockIdx.x * 64 + wave * 16;

    int irow = min(ibase + m, I_NUM - 1);
    const float* arow = ifea + (size_t)irow * F_IT + q * 8;

    f32x4 av[4];
#pragma unroll
    for (int n = 0; n < 4; n++) av[n] = (f32x4){0.f, 0.f, 0.f, 0.f};

#pragma unroll
    for (int c = 0; c < 12; c++) {
        float4 fa0 = ((const float4*)(arow + c * 32))[0];
        float4 fa1 = ((const float4*)(arow + c * 32))[1];
        bf16x8 af;
        af[0] = (short)f2bf(fa0.x); af[1] = (short)f2bf(fa0.y);
        af[2] = (short)f2bf(fa0.z); af[3] = (short)f2bf(fa0.w);
        af[4] = (short)f2bf(fa1.x); af[5] = (short)f2bf(fa1.y);
        af[6] = (short)f2bf(fa1.z); af[7] = (short)f2bf(fa1.w);
#pragma unroll
        for (int n = 0; n < 4; n++) {
            bf16x8 bf = *(const bf16x8*)(wbf + (size_t)(n * 16 + m) * F_IT + c * 32 + q * 8);
            av[n] = __builtin_amdgcn_mfma_f32_16x16x32_bf16(af, bf, av[n], 0, 0, 0);
        }
    }

    // C/D layout: col = lane&15 (= dim within 16), row = (lane>>4)*4 + reg (= item)
#pragma unroll
    for (int n = 0; n < 4; n++) {
        int dim = n * 16 + m;
        float bb = b[dim];
        float gg = gi[dim] + gi[64 + dim] + gi[128 + dim];
#pragma unroll
        for (int r = 0; r < 4; r++) {
            int item = ibase + q * 4 + r;
            if (item < I_NUM) {
                float v = tanhf(av[n][r] + bb) + gg;
                size_t o = (size_t)(U_NUM + item) * D + dim;
                ego[o] = v;
                egob[o] = f2bf(v);
            }
        }
    }
}

// ---------------- ego norms ----------------
__global__ void k_norm(const float* __restrict__ ego, float* __restrict__ nrm) {
    int t = blockIdx.x * 256 + threadIdx.x;   // exact N*16 grid
    int r = t >> 4, l = t & 15;
    float4 e = ((const float4*)ego)[r * 16 + l];
    float s = e.x * e.x + e.y * e.y + e.z * e.z + e.w * e.w;
    s += __shfl_xor(s, 1);
    s += __shfl_xor(s, 2);
    s += __shfl_xor(s, 4);
    s += __shfl_xor(s, 8);
    if (l == 0) nrm[r] = fmaxf(sqrtf(s), EPSV);
}

// ---------------- one GCN layer: SpMM + cosine rescale, bf16 in/out ----------------
// 8 lanes/row. Preload all 32 bucket slots (4 x 8B per lane), shuffle-broadcast
// per edge, issue 8 independent gathers per chunk (latency hiding).
__global__ __launch_bounds__(256) void k_spmm(const ushort_t* __restrict__ xb,
                                              const ushort_t* __restrict__ egob,
                                              const float* __restrict__ nrm,
                                              const int* __restrict__ cnt,
                                              const int2* __restrict__ bkt,
                                              ushort_t* __restrict__ xob) {
    int t = blockIdx.x * 256 + threadIdx.x;
    int r = t >> 3, l = t & 7;
    if (r >= N_NUM) return;
    int deg = min(cnt[r], CAP);
    const int2* bp = bkt + (size_t)r * CAP;

    // preload bucket row cooperatively (always in-bounds; garbage beyond deg masked)
    int2 eb0 = bp[l], eb1 = bp[l + 8], eb2 = bp[l + 16], eb3 = bp[l + 24];

    float a[8];
#pragma unroll
    for (int j = 0; j < 8; j++) a[j] = 0.f;

    int nch = (deg + 7) >> 3;
    for (int k = 0; k < nch; k++) {
        int2 e = (k == 0) ? eb0 : (k == 1) ? eb1 : (k == 2) ? eb2 : eb3;
#pragma unroll
        for (int j = 0; j < 8; j++) {
            int cc = __shfl(e.x, j, 8);
            int vi = __shfl(e.y, j, 8);
            bool act = (k * 8 + j) < deg;
            float v = act ? __int_as_float(vi) : 0.f;
            cc = act ? cc : 0;
            uint4 xv = ((const uint4*)xb)[(size_t)cc * 8 + l];
            a[0] += v * bfu2f(xv.x & 0xffffu); a[1] += v * bfu2f(xv.x >> 16);
            a[2] += v * bfu2f(xv.y & 0xffffu); a[3] += v * bfu2f(xv.y >> 16);
            a[4] += v * bfu2f(xv.z & 0xffffu); a[5] += v * bfu2f(xv.z >> 16);
            a[6] += v * bfu2f(xv.w & 0xffffu); a[7] += v * bfu2f(xv.w >> 16);
        }
    }

    uint4 ev = ((const uint4*)egob)[(size_t)r * 8 + l];
    float dot = a[0] * bfu2f(ev.x & 0xffffu) + a[1] * bfu2f(ev.x >> 16)
              + a[2] * bfu2f(ev.y & 0xffffu) + a[3] * bfu2f(ev.y >> 16)
              + a[4] * bfu2f(ev.z & 0xffffu) + a[5] * bfu2f(ev.z >> 16)
              + a[6] * bfu2f(ev.w & 0xffffu) + a[7] * bfu2f(ev.w >> 16);
    float nx = a[0] * a[0] + a[1] * a[1] + a[2] * a[2] + a[3] * a[3]
             + a[4] * a[4] + a[5] * a[5] + a[6] * a[6] + a[7] * a[7];
    dot += __shfl_xor(dot, 1); nx += __shfl_xor(nx, 1);
    dot += __shfl_xor(dot, 2); nx += __shfl_xor(nx, 2);
    dot += __shfl_xor(dot, 4); nx += __shfl_xor(nx, 4);
    float wgt = dot / (fmaxf(sqrtf(nx), EPSV) * nrm[r]);

    uint4 ov;
    ov.x = (uint_t)f2bf(wgt * a[0]) | ((uint_t)f2bf(wgt * a[1]) << 16);
    ov.y = (uint_t)f2bf(wgt * a[2]) | ((uint_t)f2bf(wgt * a[3]) << 16);
    ov.z = (uint_t)f2bf(wgt * a[4]) | ((uint_t)f2bf(wgt * a[5]) << 16);
    ov.w = (uint_t)f2bf(wgt * a[6]) | ((uint_t)f2bf(wgt * a[7]) << 16);
    ((uint4*)xob)[(size_t)r * 8 + l] = ov;
}

// ---------------- final: out = ego + x1 + x2 + x3 + x4 ----------------
__global__ void k_out(const float* __restrict__ ego,
                      const ushort_t* __restrict__ x1, const ushort_t* __restrict__ x2,
                      const ushort_t* __restrict__ x3, const ushort_t* __restrict__ x4,
                      float* __restrict__ out) {
    int t = blockIdx.x * 256 + threadIdx.x;
    if (t >= N_NUM * 8) return;
    size_t b = (size_t)t * 8;
    float4 s0 = ((const float4*)(ego + b))[0];
    float4 s1 = ((const float4*)(ego + b))[1];
    uint4 u1 = ((const uint4*)x1)[t], u2 = ((const uint4*)x2)[t];
    uint4 u3 = ((const uint4*)x3)[t], u4 = ((const uint4*)x4)[t];
#define ADD8(u) \
    s0.x += bfu2f(u.x & 0xffffu); s0.y += bfu2f(u.x >> 16); \
    s0.z += bfu2f(u.y & 0xffffu); s0.w += bfu2f(u.y >> 16); \
    s1.x += bfu2f(u.z & 0xffffu); s1.y += bfu2f(u.z >> 16); \
    s1.z += bfu2f(u.w & 0xffffu); s1.w += bfu2f(u.w >> 16);
    ADD8(u1) ADD8(u2) ADD8(u3) ADD8(u4)
#undef ADD8
    ((float4*)(out + b))[0] = s0;
    ((float4*)(out + b))[1] = s1;
}

extern "C" void kernel_launch(void* const* d_in, const int* in_sizes, int n_in,
                              void* d_out, int out_size, void* d_ws, size_t ws_size,
                              hipStream_t stream) {
    const int*   adj_row  = (const int*)d_in[0];
    const int*   adj_col  = (const int*)d_in[1];
    const float* adj_val  = (const float*)d_in[2];
    const float* user_fea = (const float*)d_in[3];
    const float* item_fea = (const float*)d_in[4];
    const float* gu       = (const float*)d_in[5];
    const float* gi       = (const float*)d_in[6];
    const float* mlp_w    = (const float*)d_in[7];
    const float* mlp_b    = (const float*)d_in[8];

    float* out = (float*)d_out;   // concat(user, item) rows = node order

    char* ws = (char*)d_ws;
    size_t off = 0;
    float*    ego  = (float*)(ws + off);    off += (size_t)N_NUM * D * 4;
    ushort_t* egob = (ushort_t*)(ws + off); off += (size_t)N_NUM * D * 2;
    ushort_t* x1   = (ushort_t*)(ws + off); off += (size_t)N_NUM * D * 2;
    ushort_t* x2   = (ushort_t*)(ws + off); off += (size_t)N_NUM * D * 2;
    ushort_t* x3   = (ushort_t*)(ws + off); off += (size_t)N_NUM * D * 2;
    ushort_t* x4   = (ushort_t*)(ws + off); off += (size_t)N_NUM * D * 2;
    float*    nrm  = (float*)(ws + off);    off += (size_t)N_NUM * 4;
    int*      cnt  = (int*)(ws + off);      off += (size_t)N_NUM * 4;
    short*    wbf  = (short*)(ws + off);    off += (size_t)D * F_IT * 2;
    off = (off + 255) & ~(size_t)255;
    int2*     bkt  = (int2*)(ws + off);     off += (size_t)N_NUM * CAP * 8;

    k_zero<<<(N_NUM + 255) / 256, 256, 0, stream>>>(cnt, N_NUM);
    k_fill<<<(E_NUM / 4 + 255) / 256, 256, 0, stream>>>(adj_row, adj_col, adj_val, cnt, bkt);
    k_wcast<<<D * F_IT / 256, 256, 0, stream>>>(mlp_w, wbf);
    k_user<<<U_NUM * D / 256, 256, 0, stream>>>(user_fea, gu, ego, egob);
    k_item<<<(I_NUM + 63) / 64, 256, 0, stream>>>(item_fea, wbf, mlp_b, gi, ego, egob);
    k_norm<<<N_NUM * 16 / 256, 256, 0, stream>>>(ego, nrm);

    int g = (N_NUM * 8 + 255) / 256;
    k_spmm<<<g, 256, 0, stream>>>(egob, egob, nrm, cnt, bkt, x1);
    k_spmm<<<g, 256, 0, stream>>>(x1,   egob, nrm, cnt, bkt, x2);
    k_spmm<<<g, 256, 0, stream>>>(x2,   egob, nrm, cnt, bkt, x3);
    k_spmm<<<g, 256, 0, stream>>>(x3,   egob, nrm, cnt, bkt, x4);

    k_out<<<g, 256, 0, stream>>>(ego, x1, x2, x3, x4, out);
}

// Round 6
// 409.857 us; speedup vs baseline: 1.6648x; 1.0481x over previous
//
#include <hip/hip_runtime.h>
#include <hip/hip_bf16.h>

#define U_NUM 100000
#define I_NUM 50000
#define N_NUM 150000
#define E_NUM 1200000
#define D 64
#define F_IT 384
#define CAP 32
#define EPSV 1e-8f
#define FXS 524288.0f          // 2^19 fixed-point scale (deterministic int accumulation)
#define FXI (1.0f / 524288.0f)

typedef unsigned short ushort_t;
typedef unsigned int uint_t;
typedef short bf16x8 __attribute__((ext_vector_type(8)));
typedef float f32x4 __attribute__((ext_vector_type(4)));

__device__ __forceinline__ ushort_t f2bf(float f) {
    uint_t x = __float_as_uint(f);
    uint_t r = x + 0x7fffu + ((x >> 16) & 1u);   // round-to-nearest-even
    return (ushort_t)(r >> 16);
}
__device__ __forceinline__ float bfu2f(uint_t u_lo16) {
    return __uint_as_float(u_lo16 << 16);
}
__device__ __forceinline__ void dec8(uint4 u, float* f) {
    f[0] = bfu2f(u.x & 0xffffu); f[1] = bfu2f(u.x >> 16);
    f[2] = bfu2f(u.y & 0xffffu); f[3] = bfu2f(u.y >> 16);
    f[4] = bfu2f(u.z & 0xffffu); f[5] = bfu2f(u.z >> 16);
    f[6] = bfu2f(u.w & 0xffffu); f[7] = bfu2f(u.w >> 16);
}

// ================= prep: zero cnt + cast weights + sum global embs =================
__global__ void k_prep(const float* __restrict__ w, const float* __restrict__ gu,
                       const float* __restrict__ gi,
                       int* __restrict__ cnt, short* __restrict__ wbf,
                       float* __restrict__ gsu, float* __restrict__ gsi) {
    int b = blockIdx.x, t = threadIdx.x;
    if (b < 586) {
        int i = b * 256 + t;
        if (i < N_NUM) cnt[i] = 0;
    } else if (b < 682) {
        int i = (b - 586) * 256 + t;   // exactly 96*256 = 24576 = D*F_IT
        wbf[i] = (short)f2bf(w[i]);
    } else {
        if (t < 64) gsu[t] = gu[t] + gu[64 + t] + gu[128 + t];
        else if (t < 128) { int d = t - 64; gsi[d] = gi[d] + gi[64 + d] + gi[128 + d]; }
    }
}

// ================= mega: fill (latency-wall) + item MLP (MFMA) + user, overlapped ==
// role striping per 9-block group: 3 fill, 2 item, 4 user -> every CU holds a mix.
// NOTE: bucket slot order is nondeterministic (atomicAdd), but spmm accumulation is
// permutation-invariant (fixed-point int), so d_out is bit-stable.
#define FILL_B 1172   // ceil(E/4/256)
#define ITEM_B 782    // ceil(I/64)
#define USER_B 1563   // ceil(U*D/16/256)

__global__ __launch_bounds__(256) void k_mega(
        const int* __restrict__ row, const int* __restrict__ col,
        const float* __restrict__ val,
        const float* __restrict__ ufea, const float* __restrict__ ifea,
        const float* __restrict__ bvec,
        const short* __restrict__ wbf,
        const float* __restrict__ gsu, const float* __restrict__ gsi,
        int* __restrict__ cnt, int2* __restrict__ bkt,
        float* __restrict__ ego, ushort_t* __restrict__ egob) {
    int b = blockIdx.x;
    int grp = b / 9, slot = b % 9;
    int tid = threadIdx.x;

    if (slot < 3) {
        // ---------------- fill role ----------------
        int fid = grp * 3 + slot;
        if (fid >= FILL_B) return;
        int t = fid * 256 + tid;
        if (t >= E_NUM / 4) return;
        int r[4], c[4];
        float v[4];
#pragma unroll
        for (int k = 0; k < 4; k++) {
            int e = t + k * (E_NUM / 4);
            r[k] = row[e]; c[k] = col[e]; v[k] = val[e];
        }
        int p[4];
#pragma unroll
        for (int k = 0; k < 4; k++) p[k] = atomicAdd(&cnt[r[k]], 1);
#pragma unroll
        for (int k = 0; k < 4; k++) {
            if (p[k] < CAP) bkt[r[k] * CAP + p[k]] = make_int2(c[k], __float_as_int(v[k]));
        }
    } else if (slot < 5) {
        // ---------------- item MLP role (MFMA, no LDS) ----------------
        int iid = grp * 2 + (slot - 3);
        if (iid >= ITEM_B) return;
        int wave = tid >> 6, lane = tid & 63;
        int q = lane >> 4, m = lane & 15;
        int ibase = iid * 64 + wave * 16;
        int irow = min(ibase + m, I_NUM - 1);
        const float* arow = ifea + (size_t)irow * F_IT + q * 8;

        f32x4 av[4];
#pragma unroll
        for (int n = 0; n < 4; n++) av[n] = (f32x4){0.f, 0.f, 0.f, 0.f};
#pragma unroll
        for (int c = 0; c < 12; c++) {
            float4 fa0 = ((const float4*)(arow + c * 32))[0];
            float4 fa1 = ((const float4*)(arow + c * 32))[1];
            bf16x8 af;
            af[0] = (short)f2bf(fa0.x); af[1] = (short)f2bf(fa0.y);
            af[2] = (short)f2bf(fa0.z); af[3] = (short)f2bf(fa0.w);
            af[4] = (short)f2bf(fa1.x); af[5] = (short)f2bf(fa1.y);
            af[6] = (short)f2bf(fa1.z); af[7] = (short)f2bf(fa1.w);
#pragma unroll
            for (int n = 0; n < 4; n++) {
                bf16x8 bf = *(const bf16x8*)(wbf + (size_t)(n * 16 + m) * F_IT + c * 32 + q * 8);
                av[n] = __builtin_amdgcn_mfma_f32_16x16x32_bf16(af, bf, av[n], 0, 0, 0);
            }
        }
        // C/D: col = lane&15 (dim), row = (lane>>4)*4 + reg (item)
#pragma unroll
        for (int n = 0; n < 4; n++) {
            int dim = n * 16 + m;
            float bb = bvec[dim];
            float gg = gsi[dim];
#pragma unroll
            for (int rr = 0; rr < 4; rr++) {
                int item = ibase + q * 4 + rr;
                if (item < I_NUM) {
                    float v = tanhf(av[n][rr] + bb) + gg;
                    size_t o = (size_t)(U_NUM + item) * D + dim;
                    ego[o] = v;
                    egob[o] = f2bf(v);
                }
            }
        }
    } else {
        // ---------------- user role: 16 floats/thread ----------------
        int uid = grp * 4 + (slot - 5);
        if (uid >= USER_B) return;
        int t = uid * 256 + tid;
        size_t base = (size_t)t * 16;
        if (base >= (size_t)U_NUM * D) return;
        int d0 = (int)(base & 63);
        float f[16];
#pragma unroll
        for (int k = 0; k < 4; k++) {
            float4 v = ((const float4*)(ufea + base))[k];
            f[4 * k] = v.x; f[4 * k + 1] = v.y; f[4 * k + 2] = v.z; f[4 * k + 3] = v.w;
        }
#pragma unroll
        for (int j = 0; j < 16; j++) f[j] += gsu[d0 + j];
#pragma unroll
        for (int k = 0; k < 4; k++) {
            ((float4*)(ego + base))[k] = make_float4(f[4 * k], f[4 * k + 1], f[4 * k + 2], f[4 * k + 3]);
        }
        uint4 u0, u1;
        u0.x = (uint_t)f2bf(f[0]) | ((uint_t)f2bf(f[1]) << 16);
        u0.y = (uint_t)f2bf(f[2]) | ((uint_t)f2bf(f[3]) << 16);
        u0.z = (uint_t)f2bf(f[4]) | ((uint_t)f2bf(f[5]) << 16);
        u0.w = (uint_t)f2bf(f[6]) | ((uint_t)f2bf(f[7]) << 16);
        u1.x = (uint_t)f2bf(f[8]) | ((uint_t)f2bf(f[9]) << 16);
        u1.y = (uint_t)f2bf(f[10]) | ((uint_t)f2bf(f[11]) << 16);
        u1.z = (uint_t)f2bf(f[12]) | ((uint_t)f2bf(f[13]) << 16);
        u1.w = (uint_t)f2bf(f[14]) | ((uint_t)f2bf(f[15]) << 16);
        ((uint4*)(egob + base))[0] = u0;
        ((uint4*)(egob + base))[1] = u1;
    }
}

// ===== spmm: 2 rows per 8-lane group, fixed-point int accumulation (order-invariant)
// VS = v * 2^19 (0 for masked slots); A[j] += rn(VS * x[j]); int add is associative.
#define ACC8(A, VS, X) \
    A[0] += __float2int_rn(VS * bfu2f(X.x & 0xffffu)); A[1] += __float2int_rn(VS * bfu2f(X.x >> 16)); \
    A[2] += __float2int_rn(VS * bfu2f(X.y & 0xffffu)); A[3] += __float2int_rn(VS * bfu2f(X.y >> 16)); \
    A[4] += __float2int_rn(VS * bfu2f(X.z & 0xffffu)); A[5] += __float2int_rn(VS * bfu2f(X.z >> 16)); \
    A[6] += __float2int_rn(VS * bfu2f(X.w & 0xffffu)); A[7] += __float2int_rn(VS * bfu2f(X.w >> 16));

__device__ __forceinline__ float row_weight(const float* a, const float* e) {
    float dot = 0.f, nx = 0.f, ne = 0.f;
#pragma unroll
    for (int j = 0; j < 8; j++) {
        dot += a[j] * e[j]; nx += a[j] * a[j]; ne += e[j] * e[j];
    }
#pragma unroll
    for (int m = 1; m < 8; m <<= 1) {
        dot += __shfl_xor(dot, m);
        nx  += __shfl_xor(nx, m);
        ne  += __shfl_xor(ne, m);
    }
    return dot / (fmaxf(sqrtf(nx), EPSV) * fmaxf(sqrtf(ne), EPSV));
}

__global__ __launch_bounds__(256) void k_spmm(const ushort_t* __restrict__ xb,
                                              const ushort_t* __restrict__ egob,
                                              const int* __restrict__ cnt,
                                              const int2* __restrict__ bkt,
                                              ushort_t* __restrict__ xob) {
    int t = blockIdx.x * 256 + threadIdx.x;
    int l = t & 7, g = t >> 3;
    if (g >= N_NUM / 2) return;
    int r0 = g * 2, r1 = r0 + 1;
    int deg0 = min(cnt[r0], CAP), deg1 = min(cnt[r1], CAP);
    const int2* bp0 = bkt + (size_t)r0 * CAP;
    const int2* bp1 = bkt + (size_t)r1 * CAP;
    int2 p0[4] = {bp0[l], bp0[l + 8], bp0[l + 16], bp0[l + 24]};
    int2 p1[4] = {bp1[l], bp1[l + 8], bp1[l + 16], bp1[l + 24]};
    int a0[8], a1[8];
#pragma unroll
    for (int j = 0; j < 8; j++) { a0[j] = 0; a1[j] = 0; }
    int dmax = max(deg0, deg1);
#pragma unroll
    for (int k = 0; k < 4; k++) {
        if (k * 8 < dmax) {
            int c0x = p0[k].x, c0y = p0[k].y, c1x = p1[k].x, c1y = p1[k].y;
#pragma unroll
            for (int j = 0; j < 8; j++) {
                int cc0 = __shfl(c0x, j, 8);
                float v0 = __int_as_float(__shfl(c0y, j, 8));
                if ((k * 8 + j) >= deg0) { cc0 = 0; v0 = 0.f; }
                uint4 xv = ((const uint4*)xb)[(size_t)cc0 * 8 + l];
                int cc1 = __shfl(c1x, j, 8);
                float v1 = __int_as_float(__shfl(c1y, j, 8));
                if ((k * 8 + j) >= deg1) { cc1 = 0; v1 = 0.f; }
                uint4 yv = ((const uint4*)xb)[(size_t)cc1 * 8 + l];
                float vs0 = v0 * FXS, vs1 = v1 * FXS;
                ACC8(a0, vs0, xv);
                ACC8(a1, vs1, yv);
            }
        }
    }
#pragma unroll
    for (int rr = 0; rr < 2; rr++) {
        int r = rr ? r1 : r0;
        const int* ai = rr ? a1 : a0;
        float a[8];
#pragma unroll
        for (int j = 0; j < 8; j++) a[j] = (float)ai[j] * FXI;
        float e[8]; dec8(((const uint4*)egob)[(size_t)r * 8 + l], e);
        float wgt = row_weight(a, e);
        uint4 ov;
        ov.x = (uint_t)f2bf(wgt * a[0]) | ((uint_t)f2bf(wgt * a[1]) << 16);
        ov.y = (uint_t)f2bf(wgt * a[2]) | ((uint_t)f2bf(wgt * a[3]) << 16);
        ov.z = (uint_t)f2bf(wgt * a[4]) | ((uint_t)f2bf(wgt * a[5]) << 16);
        ov.w = (uint_t)f2bf(wgt * a[6]) | ((uint_t)f2bf(wgt * a[7]) << 16);
        ((uint4*)xob)[(size_t)r * 8 + l] = ov;
    }
}

// ================= layer 4 + final sum: out = ego + x1 + x2 + x3 + o4 ==============
__global__ __launch_bounds__(256) void k_spmm4(const ushort_t* __restrict__ x3,
                                               const ushort_t* __restrict__ x1,
                                               const ushort_t* __restrict__ x2,
                                               const float* __restrict__ ego,
                                               const int* __restrict__ cnt,
                                               const int2* __restrict__ bkt,
                                               float* __restrict__ out) {
    int t = blockIdx.x * 256 + threadIdx.x;
    int l = t & 7, g = t >> 3;
    if (g >= N_NUM / 2) return;
    int r0 = g * 2, r1 = r0 + 1;
    int deg0 = min(cnt[r0], CAP), deg1 = min(cnt[r1], CAP);
    const int2* bp0 = bkt + (size_t)r0 * CAP;
    const int2* bp1 = bkt + (size_t)r1 * CAP;
    int2 p0[4] = {bp0[l], bp0[l + 8], bp0[l + 16], bp0[l + 24]};
    int2 p1[4] = {bp1[l], bp1[l + 8], bp1[l + 16], bp1[l + 24]};
    int a0[8], a1[8];
#pragma unroll
    for (int j = 0; j < 8; j++) { a0[j] = 0; a1[j] = 0; }
    int dmax = max(deg0, deg1);
#pragma unroll
    for (int k = 0; k < 4; k++) {
        if (k * 8 < dmax) {
            int c0x = p0[k].x, c0y = p0[k].y, c1x = p1[k].x, c1y = p1[k].y;
#pragma unroll
            for (int j = 0; j < 8; j++) {
                int cc0 = __shfl(c0x, j, 8);
                float v0 = __int_as_float(__shfl(c0y, j, 8));
                if ((k * 8 + j) >= deg0) { cc0 = 0; v0 = 0.f; }
                uint4 xv = ((const uint4*)x3)[(size_t)cc0 * 8 + l];
                int cc1 = __shfl(c1x, j, 8);
                float v1 = __int_as_float(__shfl(c1y, j, 8));
                if ((k * 8 + j) >= deg1) { cc1 = 0; v1 = 0.f; }
                uint4 yv = ((const uint4*)x3)[(size_t)cc1 * 8 + l];
                float vs0 = v0 * FXS, vs1 = v1 * FXS;
                ACC8(a0, vs0, xv);
                ACC8(a1, vs1, yv);
            }
        }
    }
#pragma unroll
    for (int rr = 0; rr < 2; rr++) {
        int r = rr ? r1 : r0;
        const int* ai = rr ? a1 : a0;
        float a[8];
#pragma unroll
        for (int j = 0; j < 8; j++) a[j] = (float)ai[j] * FXI;
        size_t rb = (size_t)r * D + l * 8;
        float e[8];
        float4 e0 = ((const float4*)(ego + rb))[0];
        float4 e1 = ((const float4*)(ego + rb))[1];
        e[0] = e0.x; e[1] = e0.y; e[2] = e0.z; e[3] = e0.w;
        e[4] = e1.x; e[5] = e1.y; e[6] = e1.z; e[7] = e1.w;
        float wgt = row_weight(a, e);
        float s[8];
        float x1d[8], x2d[8], x3d[8];
        dec8(((const uint4*)x1)[(size_t)r * 8 + l], x1d);
        dec8(((const uint4*)x2)[(size_t)r * 8 + l], x2d);
        dec8(((const uint4*)x3)[(size_t)r * 8 + l], x3d);
#pragma unroll
        for (int j = 0; j < 8; j++) s[j] = e[j] + x1d[j] + x2d[j] + x3d[j] + wgt * a[j];
        ((float4*)(out + rb))[0] = make_float4(s[0], s[1], s[2], s[3]);
        ((float4*)(out + rb))[1] = make_float4(s[4], s[5], s[6], s[7]);
    }
}

extern "C" void kernel_launch(void* const* d_in, const int* in_sizes, int n_in,
                              void* d_out, int out_size, void* d_ws, size_t ws_size,
                              hipStream_t stream) {
    const int*   adj_row  = (const int*)d_in[0];
    const int*   adj_col  = (const int*)d_in[1];
    const float* adj_val  = (const float*)d_in[2];
    const float* user_fea = (const float*)d_in[3];
    const float* item_fea = (const float*)d_in[4];
    const float* gu       = (const float*)d_in[5];
    const float* gi       = (const float*)d_in[6];
    const float* mlp_w    = (const float*)d_in[7];
    const float* mlp_b    = (const float*)d_in[8];

    float* out = (float*)d_out;

    char* ws = (char*)d_ws;
    size_t off = 0;
    float*    ego  = (float*)(ws + off);    off += (size_t)N_NUM * D * 4;
    ushort_t* egob = (ushort_t*)(ws + off); off += (size_t)N_NUM * D * 2;
    ushort_t* x1   = (ushort_t*)(ws + off); off += (size_t)N_NUM * D * 2;
    ushort_t* x2   = (ushort_t*)(ws + off); off += (size_t)N_NUM * D * 2;
    ushort_t* x3   = (ushort_t*)(ws + off); off += (size_t)N_NUM * D * 2;
    int*      cnt  = (int*)(ws + off);      off += (size_t)N_NUM * 4;
    short*    wbf  = (short*)(ws + off);    off += (size_t)D * F_IT * 2;
    float*    gsu  = (float*)(ws + off);    off += 64 * 4;
    float*    gsi  = (float*)(ws + off);    off += 64 * 4;
    off = (off + 255) & ~(size_t)255;
    int2*     bkt  = (int2*)(ws + off);     off += (size_t)N_NUM * CAP * 8;

    k_prep<<<683, 256, 0, stream>>>(mlp_w, gu, gi, cnt, wbf, gsu, gsi);
    k_mega<<<391 * 9, 256, 0, stream>>>(adj_row, adj_col, adj_val, user_fea, item_fea,
                                        mlp_b, wbf, gsu, gsi, cnt, bkt, ego, egob);
    int g = (N_NUM / 2 * 8 + 255) / 256;
    k_spmm<<<g, 256, 0, stream>>>(egob, egob, cnt, bkt, x1);
    k_spmm<<<g, 256, 0, stream>>>(x1,   egob, cnt, bkt, x2);
    k_spmm<<<g, 256, 0, stream>>>(x2,   egob, cnt, bkt, x3);
    k_spmm4<<<g, 256, 0, stream>>>(x3, x1, x2, ego, cnt, bkt, out);
}